// Round 1
// 1236.390 us; speedup vs baseline: 1.1206x; 1.1206x over previous
//
#include <hip/hip_runtime.h>
#include <math.h>

typedef __attribute__((ext_vector_type(8))) short bf16x8;
typedef __attribute__((ext_vector_type(4))) float f32x4;

#define MFMA16(a, b, c) __builtin_amdgcn_mfma_f32_16x16x32_bf16(a, b, c, 0, 0, 0)

// global->LDS async copy, 16B per lane. LDS dest = wave-uniform base + lane*16.
#define GLD_LDS16(g, l)                                                          \
    __builtin_amdgcn_global_load_lds(                                            \
        (const __attribute__((address_space(1))) unsigned int*)(g),              \
        (__attribute__((address_space(3))) unsigned int*)(l), 16, 0, 0)

__device__ __forceinline__ short f2bf(float f) {
    union { float f; unsigned int u; } v; v.f = f;
    unsigned int u = v.u;
    u += 0x7FFFu + ((u >> 16) & 1u);   // round-to-nearest-even
    return (short)(u >> 16);
}

__device__ __forceinline__ short f2bf_trunc(float f) {
    union { float f; unsigned int u; } v; v.f = f;
    return (short)(v.u >> 16);
}

__device__ __forceinline__ float fexp2(float x) {
#if __has_builtin(__builtin_amdgcn_exp2f)
    return __builtin_amdgcn_exp2f(x);
#else
    return __expf(x * 0.6931471805599453f);
#endif
}

// ---------------------------------------------------------------- convert
__global__ __launch_bounds__(256) void cvt_kernel(const float* __restrict__ src,
                                                  short* __restrict__ dst, int n4) {
    int i = blockIdx.x * 256 + threadIdx.x;
    if (i >= n4) return;
    float4 v = ((const float4*)src)[i];
    short4 o;
    o.x = f2bf(v.x); o.y = f2bf(v.y); o.z = f2bf(v.z); o.w = f2bf(v.w);
    ((short4*)dst)[i] = o;
}

// ---------------------------------------------------- combined alibi/mask bias (x log2e)
__global__ __launch_bounds__(256) void bias_prep_kernel(const float* __restrict__ alibi,
                                                        const int* __restrict__ amask,
                                                        float* __restrict__ cb) {
    int i = blockIdx.x * 256 + threadIdx.x;   // i over 64*2048
    int bh = i >> 11, k = i & 2047;
    int b = bh >> 5;
    cb[i] = (amask[b * 2048 + k] > 0) ? alibi[i] * 1.4426950408889634f : -3.0e38f;
}

// ------------------------------------------------- transpose fp32[R][C] -> bf16[C][R]
__global__ __launch_bounds__(256) void transpose_cvt_kernel(const float* __restrict__ src,
                                                            short* __restrict__ dst,
                                                            int R, int C) {
    __shared__ short tile[32][33];
    const int t = threadIdx.x;
    const int r0 = blockIdx.y << 5, c0 = blockIdx.x << 5;
    {
        int tr = t >> 3, tc = (t & 7) << 2;
        float4 v = *(const float4*)(src + (size_t)(r0 + tr) * C + c0 + tc);
        tile[tr][tc + 0] = f2bf(v.x);
        tile[tr][tc + 1] = f2bf(v.y);
        tile[tr][tc + 2] = f2bf(v.z);
        tile[tr][tc + 3] = f2bf(v.w);
    }
    __syncthreads();
    {
        int on = t >> 3, ok = (t & 7) << 2;
        short4 o;
        o.x = tile[ok + 0][on]; o.y = tile[ok + 1][on];
        o.z = tile[ok + 2][on]; o.w = tile[ok + 3][on];
        *(short4*)(dst + (size_t)(c0 + on) * R + r0 + ok) = o;
    }
}

// ---------------------------------------------------------------- QKV GEMM
// 256x256 tile, BK=32, 8 waves (2M x 4N), 4 LDS buffers, depth-3 prefetch.
// T2 swizzle (byte bits 4-5 ^= bits 7-8, involution): linear gld_lds dest +
// pre-swizzled global source + swizzled ds_read. Counted vmcnt(8) boundary.
__global__ __launch_bounds__(512, 2) void qkv_gemm_kernel(const short* __restrict__ A,
                                                          const short* __restrict__ Bt,
                                                          const float* __restrict__ bias,
                                                          short* __restrict__ Qo,
                                                          short* __restrict__ Ko,
                                                          short* __restrict__ Vo) {
    __shared__ __attribute__((aligned(16))) short Al[4][8192];  // [buf][256r x 32k]
    __shared__ __attribute__((aligned(16))) short Bl[4][8192];
    const int t = threadIdx.x;
    const int lane = t & 63;
    const int w = t >> 6;          // 0..7
    const int wm = w >> 2;         // 0..1  -> 128 rows
    const int wn = w & 3;          // 0..3  -> 64 cols
    const int l16 = lane & 15;
    const int quad = lane >> 4;
    const int m0 = blockIdx.x << 8;
    const int n0 = blockIdx.y << 8;

    // staging: wave w stages rows w*32..w*32+31 of A-tile and B-tile.
    // per gld_lds (1KB): 16 rows; lane covers row (lane>>2), 16B slot (lane&3).
    // source k-slot pre-swizzled: slot ^ ((row>>1)&3) == (lane&3) ^ ((lane>>3)&3).
    const int srow = lane >> 2;
    const int skoff = (((lane & 3) ^ ((lane >> 3) & 3)) << 3);   // shorts
    const short* pA0 = A + (size_t)(m0 + (w << 5) + srow) * 4096 + skoff;
    const short* pA1 = pA0 + (size_t)16 * 4096;
    const short* pB0 = Bt + (size_t)(n0 + (w << 5) + srow) * 4096 + skoff;
    const short* pB1 = pB0 + (size_t)16 * 4096;

    // swizzled read offsets (shorts): row*32 + (quad ^ ((row>>1)&3))*8,
    // and (row>>1)&3 == (l16>>1)&3 for all fragments.
    const int qs = quad ^ ((l16 >> 1) & 3);
    const int aoff = ((wm << 7) + l16) * 32 + (qs << 3);
    const int boff = ((wn << 6) + l16) * 32 + (qs << 3);

    f32x4 acc[8][4];
#pragma unroll
    for (int i = 0; i < 8; ++i)
#pragma unroll
        for (int j = 0; j < 4; ++j) acc[i][j] = (f32x4){0.f, 0.f, 0.f, 0.f};

#define STAGE_A(tt) do {                                                   \
        GLD_LDS16(pA0 + (size_t)(tt) * 32, &Al[(tt) & 3][w << 10]);        \
        GLD_LDS16(pA1 + (size_t)(tt) * 32, &Al[(tt) & 3][(w << 10) + 512]);\
    } while (0)
#define STAGE_B(tt) do {                                                   \
        GLD_LDS16(pB0 + (size_t)(tt) * 32, &Bl[(tt) & 3][w << 10]);        \
        GLD_LDS16(pB1 + (size_t)(tt) * 32, &Bl[(tt) & 3][(w << 10) + 512]);\
    } while (0)

    STAGE_A(0); STAGE_B(0);
    STAGE_A(1); STAGE_B(1);
    STAGE_A(2); STAGE_B(2);
    asm volatile("s_waitcnt vmcnt(8)" ::: "memory");   // tile 0 landed
    __builtin_amdgcn_s_barrier();
    __builtin_amdgcn_sched_barrier(0);

    for (int kt = 0; kt < 128; ++kt) {
        const short* ab = &Al[kt & 3][0];
        const short* bb = &Bl[kt & 3][0];
        bf16x8 bfr[4], afr[4];
        // phase 0: rows 0-63 of wave block, all 64 cols
#pragma unroll
        for (int j = 0; j < 4; ++j) bfr[j] = *(const bf16x8*)(bb + boff + (j << 9));
#pragma unroll
        for (int i = 0; i < 4; ++i) afr[i] = *(const bf16x8*)(ab + aoff + (i << 9));
        if (kt < 125) STAGE_A(kt + 3);
        __builtin_amdgcn_s_setprio(1);
#pragma unroll
        for (int i = 0; i < 4; ++i)
#pragma unroll
            for (int j = 0; j < 4; ++j) acc[i][j] = MFMA16(afr[i], bfr[j], acc[i][j]);
        __builtin_amdgcn_s_setprio(0);
        __builtin_amdgcn_s_barrier();
        // phase 1: rows 64-127, B frags reused from registers
#pragma unroll
        for (int i = 0; i < 4; ++i) afr[i] = *(const bf16x8*)(ab + aoff + ((i + 4) << 9));
        if (kt < 125) STAGE_B(kt + 3);
        __builtin_amdgcn_s_setprio(1);
#pragma unroll
        for (int i = 0; i < 4; ++i)
#pragma unroll
            for (int j = 0; j < 4; ++j) acc[i + 4][j] = MFMA16(afr[i], bfr[j], acc[i + 4][j]);
        __builtin_amdgcn_s_setprio(0);
        // boundary: keep 2 tiles (8 loads) in flight; never drain in main loop
        if (kt < 125)       { asm volatile("s_waitcnt vmcnt(8)" ::: "memory"); }
        else if (kt == 125) { asm volatile("s_waitcnt vmcnt(4)" ::: "memory"); }
        else if (kt == 126) { asm volatile("s_waitcnt vmcnt(0)" ::: "memory"); }
        if (kt < 127) {
            __builtin_amdgcn_s_barrier();
            __builtin_amdgcn_sched_barrier(0);
        }
    }
#undef STAGE_A
#undef STAGE_B

    // Q pre-scaled by log2(e)/sqrt(128) for base-2 softmax
    const float qscale = 0.12751740806338946f;
#pragma unroll
    for (int j = 0; j < 4; ++j) {
        int gn = n0 + (wn << 6) + (j << 4) + l16;
        float bv = bias[gn];
        int head = gn / 384, f = gn - head * 384;
#pragma unroll
        for (int i = 0; i < 8; ++i) {
#pragma unroll
            for (int r = 0; r < 4; ++r) {
                int gm = m0 + (wm << 7) + (i << 4) + (quad << 2) + r;
                float v = acc[i][j][r] + bv;
                int b = gm >> 11, s = gm & 2047;
                int bhh = (b << 5) + head;
                if (f < 128) {
                    Qo[((size_t)bhh * 2048 + s) * 128 + f] = f2bf(v * qscale);
                } else if (f < 256) {
                    Ko[((size_t)bhh * 2048 + s) * 128 + (f - 128)] = f2bf(v);
                } else {
                    Vo[((size_t)bhh * 128 + (f - 256)) * 2048 + s] = f2bf(v);
                }
            }
        }
    }
}

// ---------------------------------------------------------------- out GEMM
// identical 256^2 deep-pipelined core, fp32 epilogue with bias.
__global__ __launch_bounds__(512, 2) void out_gemm_kernel(const short* __restrict__ A,
                                                          const short* __restrict__ Bt,
                                                          const float* __restrict__ bias,
                                                          float* __restrict__ Co) {
    __shared__ __attribute__((aligned(16))) short Al[4][8192];
    __shared__ __attribute__((aligned(16))) short Bl[4][8192];
    const int t = threadIdx.x;
    const int lane = t & 63;
    const int w = t >> 6;
    const int wm = w >> 2;
    const int wn = w & 3;
    const int l16 = lane & 15;
    const int quad = lane >> 4;
    const int m0 = blockIdx.x << 8;
    const int n0 = blockIdx.y << 8;

    const int srow = lane >> 2;
    const int skoff = (((lane & 3) ^ ((lane >> 3) & 3)) << 3);
    const short* pA0 = A + (size_t)(m0 + (w << 5) + srow) * 4096 + skoff;
    const short* pA1 = pA0 + (size_t)16 * 4096;
    const short* pB0 = Bt + (size_t)(n0 + (w << 5) + srow) * 4096 + skoff;
    const short* pB1 = pB0 + (size_t)16 * 4096;

    const int qs = quad ^ ((l16 >> 1) & 3);
    const int aoff = ((wm << 7) + l16) * 32 + (qs << 3);
    const int boff = ((wn << 6) + l16) * 32 + (qs << 3);

    f32x4 acc[8][4];
#pragma unroll
    for (int i = 0; i < 8; ++i)
#pragma unroll
        for (int j = 0; j < 4; ++j) acc[i][j] = (f32x4){0.f, 0.f, 0.f, 0.f};

#define STAGE_A(tt) do {                                                   \
        GLD_LDS16(pA0 + (size_t)(tt) * 32, &Al[(tt) & 3][w << 10]);        \
        GLD_LDS16(pA1 + (size_t)(tt) * 32, &Al[(tt) & 3][(w << 10) + 512]);\
    } while (0)
#define STAGE_B(tt) do {                                                   \
        GLD_LDS16(pB0 + (size_t)(tt) * 32, &Bl[(tt) & 3][w << 10]);        \
        GLD_LDS16(pB1 + (size_t)(tt) * 32, &Bl[(tt) & 3][(w << 10) + 512]);\
    } while (0)

    STAGE_A(0); STAGE_B(0);
    STAGE_A(1); STAGE_B(1);
    STAGE_A(2); STAGE_B(2);
    asm volatile("s_waitcnt vmcnt(8)" ::: "memory");
    __builtin_amdgcn_s_barrier();
    __builtin_amdgcn_sched_barrier(0);

    for (int kt = 0; kt < 128; ++kt) {
        const short* ab = &Al[kt & 3][0];
        const short* bb = &Bl[kt & 3][0];
        bf16x8 bfr[4], afr[4];
#pragma unroll
        for (int j = 0; j < 4; ++j) bfr[j] = *(const bf16x8*)(bb + boff + (j << 9));
#pragma unroll
        for (int i = 0; i < 4; ++i) afr[i] = *(const bf16x8*)(ab + aoff + (i << 9));
        if (kt < 125) STAGE_A(kt + 3);
        __builtin_amdgcn_s_setprio(1);
#pragma unroll
        for (int i = 0; i < 4; ++i)
#pragma unroll
            for (int j = 0; j < 4; ++j) acc[i][j] = MFMA16(afr[i], bfr[j], acc[i][j]);
        __builtin_amdgcn_s_setprio(0);
        __builtin_amdgcn_s_barrier();
#pragma unroll
        for (int i = 0; i < 4; ++i) afr[i] = *(const bf16x8*)(ab + aoff + ((i + 4) << 9));
        if (kt < 125) STAGE_B(kt + 3);
        __builtin_amdgcn_s_setprio(1);
#pragma unroll
        for (int i = 0; i < 4; ++i)
#pragma unroll
            for (int j = 0; j < 4; ++j) acc[i + 4][j] = MFMA16(afr[i], bfr[j], acc[i + 4][j]);
        __builtin_amdgcn_s_setprio(0);
        if (kt < 125)       { asm volatile("s_waitcnt vmcnt(8)" ::: "memory"); }
        else if (kt == 125) { asm volatile("s_waitcnt vmcnt(4)" ::: "memory"); }
        else if (kt == 126) { asm volatile("s_waitcnt vmcnt(0)" ::: "memory"); }
        if (kt < 127) {
            __builtin_amdgcn_s_barrier();
            __builtin_amdgcn_sched_barrier(0);
        }
    }
#undef STAGE_A
#undef STAGE_B

#pragma unroll
    for (int j = 0; j < 4; ++j) {
        int gn = n0 + (wn << 6) + (j << 4) + l16;
        float bv = bias[gn];
#pragma unroll
        for (int i = 0; i < 8; ++i) {
#pragma unroll
            for (int r = 0; r < 4; ++r) {
                int gm = m0 + (wm << 7) + (i << 4) + (quad << 2) + r;
                Co[(size_t)gm * 4096 + gn] = acc[i][j][r] + bv;
            }
        }
    }
}

// ---------------------------------------------------------------- flash attention
// grid (32, 64): qt = 31-bx (heavy first), bh = by. Base-2 online softmax,
// l via ones-column in V (MFMA computes row sums), diag-tile-only masking.
__global__ __launch_bounds__(256) void attn_kernel(const short* __restrict__ Q,
                                                   const short* __restrict__ Kt,
                                                   const short* __restrict__ Vt,
                                                   const float* __restrict__ cbias,
                                                   short* __restrict__ Ot) {
    __shared__ short Ks[64][132];    // [key][d]
    __shared__ short Vs[144][68];    // [d][key]; rows 128..143: ones-column block
    __shared__ short Ps[4][16][68];  // per-wave P tile [q][key]
    const int t = threadIdx.x;
    const int w = t >> 6;
    const int lane = t & 63;
    const int l16 = lane & 15;
    const int quad = lane >> 4;
    const int qt = 31 - blockIdx.x;
    const int bh = blockIdx.y;
    const int b = bh >> 5;
    const int h = bh & 31;
    const int q0t = qt << 6;

    const short* Qp = Q + (size_t)bh * 2048 * 128;
    const short* Kp = Kt + (size_t)bh * 2048 * 128;
    const short* Vp = Vt + (size_t)bh * 128 * 2048;
    const float* cb = cbias + (size_t)bh * 2048;

    const int kr = t >> 4, kc = (t & 15) << 3;
    const int vr = t >> 3, vc = (t & 7) << 3;

    // ones-column block: Vs row 128 = 1.0 (keys 0..63), rows 129..143 = 0. Written once.
    for (int idx = t; idx < 16 * 68; idx += 256) {
        int rr = idx / 68, cc = idx - rr * 68;
        Vs[128 + rr][cc] = (rr == 0 && cc < 64) ? (short)0x3F80 : (short)0;
    }

    bf16x8 aq[4];
    const int myq = q0t + (w << 4) + l16;
#pragma unroll
    for (int kd = 0; kd < 4; ++kd)
        aq[kd] = *(const bf16x8*)(Qp + (size_t)myq * 128 + (kd << 5) + (quad << 3));

    f32x4 acc[9];   // [0..7]: O columns; [8]: l in column 0
#pragma unroll
    for (int c = 0; c < 9; ++c) acc[c] = (f32x4){0.f, 0.f, 0.f, 0.f};
    float mrow[4];
#pragma unroll
    for (int r = 0; r < 4; ++r) mrow[r] = -3.0e38f;

    const int ktiles = qt + 1;

    bf16x8 Kreg[4], Vreg[4];
#pragma unroll
    for (int i = 0; i < 4; ++i) {
        Kreg[i] = *(const bf16x8*)(Kp + (size_t)(kr + (i << 4)) * 128 + kc);
        Vreg[i] = *(const bf16x8*)(Vp + (size_t)(vr + (i << 5)) * 2048 + vc);
    }

    for (int kt = 0; kt < ktiles; ++kt) {
        const int kk = kt << 6;
        __syncthreads();
#pragma unroll
        for (int i = 0; i < 4; ++i) {
            *(bf16x8*)&Ks[kr + (i << 4)][kc] = Kreg[i];
            *(bf16x8*)&Vs[vr + (i << 5)][vc] = Vreg[i];
        }
        if (kt + 1 < ktiles) {
            const int nk = kk + 64;
#pragma unroll
            for (int i = 0; i < 4; ++i) {
                Kreg[i] = *(const bf16x8*)(Kp + (size_t)(nk + kr + (i << 4)) * 128 + kc);
                Vreg[i] = *(const bf16x8*)(Vp + (size_t)(vr + (i << 5)) * 2048 + nk + vc);
            }
        }
        __syncthreads();

        float biasv[4];
#pragma unroll
        for (int j = 0; j < 4; ++j)
            biasv[j] = cb[kk + (j << 4) + l16];

        f32x4 sf[4];
#pragma unroll
        for (int nb = 0; nb < 4; ++nb) {
            sf[nb] = (f32x4){0.f, 0.f, 0.f, 0.f};
#pragma unroll
            for (int kd = 0; kd < 4; ++kd) {
                bf16x8 bk = *(const bf16x8*)&Ks[(nb << 4) + l16][(kd << 5) + (quad << 3)];
                sf[nb] = MFMA16(aq[kd], bk, sf[nb]);
            }
        }

        const int qrb = q0t + (w << 4) + (quad << 2);
        const bool diag = (kt == ktiles - 1);   // only the last tile straddles causality
        float alpha[4];
#pragma unroll
        for (int r = 0; r < 4; ++r) {
            float s[4];
#pragma unroll
            for (int j = 0; j < 4; ++j) s[j] = sf[j][r] + biasv[j];
            if (diag) {
                int qr = qrb + r;
#pragma unroll
                for (int j = 0; j < 4; ++j)
                    if (kk + (j << 4) + l16 > qr) s[j] = -3.0e38f;
            }
            float mx = fmaxf(fmaxf(s[0], s[1]), fmaxf(s[2], s[3]));
            mx = fmaxf(mx, __shfl_xor(mx, 1));
            mx = fmaxf(mx, __shfl_xor(mx, 2));
            mx = fmaxf(mx, __shfl_xor(mx, 4));
            mx = fmaxf(mx, __shfl_xor(mx, 8));
            float mnew = fmaxf(mrow[r], mx);
            alpha[r] = fexp2(mrow[r] - mnew);
            mrow[r] = mnew;
            int pq = (quad << 2) + r;
#pragma unroll
            for (int j = 0; j < 4; ++j)
                Ps[w][pq][(j << 4) + l16] = f2bf_trunc(fexp2(s[j] - mnew));
        }

        // PV (+ l in frag 8 via ones-column); same-wave LDS write->read, no barrier
        bf16x8 ap0 = *(const bf16x8*)&Ps[w][l16][quad << 3];
        bf16x8 ap1 = *(const bf16x8*)&Ps[w][l16][32 + (quad << 3)];
#pragma unroll
        for (int c = 0; c < 9; ++c) {
            bf16x8 bv0 = *(const bf16x8*)&Vs[(c << 4) + l16][quad << 3];
            bf16x8 bv1 = *(const bf16x8*)&Vs[(c << 4) + l16][32 + (quad << 3)];
            f32x4 ac = acc[c];
            ac[0] *= alpha[0]; ac[1] *= alpha[1]; ac[2] *= alpha[2]; ac[3] *= alpha[3];
            ac = MFMA16(ap0, bv0, ac);
            acc[c] = MFMA16(ap1, bv1, ac);
        }
    }

    // l lives in acc[8] column 0 (lanes with l16==0); broadcast within row group
    float inv[4];
#pragma unroll
    for (int r = 0; r < 4; ++r) {
        float l = __shfl(acc[8][r], quad << 4);
        inv[r] = (l > 0.f) ? 1.0f / l : 0.f;
    }
    const int qbase = q0t + (w << 4) + (quad << 2);
#pragma unroll
    for (int c = 0; c < 8; ++c) {
        int d = (c << 4) + l16;
#pragma unroll
        for (int r = 0; r < 4; ++r) {
            int q = qbase + r;
            Ot[(size_t)(b * 2048 + q) * 4096 + h * 128 + d] = f2bf(acc[c][r] * inv[r]);
        }
    }
}

// ---------------------------------------------------------------- launch
extern "C" void kernel_launch(void* const* d_in, const int* in_sizes, int n_in,
                              void* d_out, int out_size, void* d_ws, size_t ws_size,
                              hipStream_t stream) {
    const float* hidden = (const float*)d_in[0];
    const float* alibi  = (const float*)d_in[1];
    const float* w_qkv  = (const float*)d_in[2];
    const float* b_qkv  = (const float*)d_in[3];
    const float* w_out  = (const float*)d_in[4];
    const float* b_out  = (const float*)d_in[5];
    const int*   amask  = (const int*)d_in[6];
    float* out = (float*)d_out;

    char* ws = (char*)d_ws;
    short* hid_bf = (short*)(ws);                       // 32 MB
    short* wqkv_t = (short*)(ws + 33554432ull);         // 96 MB
    short* wout_t = wqkv_t;                             // 32 MB, reuses wqkv_t region
    float* cbias  = (float*)(ws + 67108864ull);         // 512 KB, after wout_t, inside old wqkv_t region
    short* Qb     = (short*)(ws + 134217728ull);
    short* Kb     = (short*)(ws + 167772160ull);
    short* Vb     = (short*)(ws + 201326592ull);
    short* attn_o = hid_bf;

    cvt_kernel<<<16384, 256, 0, stream>>>(hidden, hid_bf, 4194304);
    transpose_cvt_kernel<<<dim3(384, 128), 256, 0, stream>>>(w_qkv, wqkv_t, 4096, 12288);
    qkv_gemm_kernel<<<dim3(16, 48), 512, 0, stream>>>(hid_bf, wqkv_t, b_qkv, Qb, Kb, Vb);
    // cbias overlaps old wqkv_t storage -> must run after qkv_gemm consumed it
    bias_prep_kernel<<<512, 256, 0, stream>>>(alibi, amask, cbias);
    transpose_cvt_kernel<<<dim3(128, 128), 256, 0, stream>>>(w_out, wout_t, 4096, 4096);
    attn_kernel<<<dim3(32, 64), 256, 0, stream>>>(Qb, Kb, Vb, cbias, attn_o);
    out_gemm_kernel<<<dim3(16, 16), 512, 0, stream>>>(attn_o, wout_t, b_out, out);
}